// Round 1
// baseline (563.333 us; speedup 1.0000x reference)
//
#include <hip/hip_runtime.h>

namespace {

constexpr int H = 1024, W = 1024, NB = 4;
constexpr int SH = 128, SW = 128;
constexpr int NPRE_IT = 8;
constexpr float LAM = 0.24f;
constexpr float KK = 0.03f * 0.03f;
constexpr float DEPS_V = 0.1f;
constexpr float FFT_SCALE = 1.0f / (1024.0f * 1024.0f);  // ortho fwd+inv combined

__device__ __forceinline__ int brev10(int i) { return (int)(__brev((unsigned)i) >> 22); }

// ---------------- shift = (min(source) <= 0.1) ? 0.1 : 0 ----------------
__global__ void k_shift(const float* __restrict__ src, float* __restrict__ shiftp) {
  int t = threadIdx.x;
  float m = 1e30f;
  for (int i = t; i < NB * SH * SW; i += 256) m = fminf(m, src[i]);
  for (int o = 32; o > 0; o >>= 1) m = fminf(m, __shfl_down(m, o));
  __shared__ float sm[4];
  if ((t & 63) == 0) sm[t >> 6] = m;
  __syncthreads();
  if (t == 0) {
    float mm = fminf(fminf(sm[0], sm[1]), fminf(sm[2], sm[3]));
    shiftp[0] = (mm <= DEPS_V) ? DEPS_V : 0.0f;
  }
}

// ---------------- 1024-pt radix-2 DIT FFT in LDS (input bit-reversed, output natural) ----
// 256 threads; sign = -1 forward, +1 inverse (unnormalized sums).
__device__ void fft1024(float2* buf, int t, float sign) {
  for (int s = 1; s <= 10; ++s) {
    int half = 1 << (s - 1);
    for (int j = t; j < 512; j += 256) {
      int grp = j >> (s - 1);
      int pos = j & (half - 1);
      int i1 = (grp << s) + pos;
      int i2 = i1 + half;
      float sn, cs;
      sincospif(sign * (float)pos / (float)half, &sn, &cs);  // angle = sign*2*pi*pos/(2*half)
      float2 u = buf[i1], v = buf[i2];
      float vr = v.x * cs - v.y * sn;
      float vi = v.x * sn + v.y * cs;
      buf[i1] = make_float2(u.x + vr, u.y + vi);
      buf[i2] = make_float2(u.x - vr, u.y - vi);
    }
    __syncthreads();
  }
}

// ---------------- forward row FFT of S = g0+g1+g2+(ybic+shift) ----------------
__global__ void k_rowfft_fwd(const float* __restrict__ guide, const float* __restrict__ ybic,
                             const float* __restrict__ shiftp, float2* __restrict__ A) {
  __shared__ float2 buf[1024];
  int b = blockIdx.y, y = blockIdx.x, t = threadIdx.x;
  float sh = shiftp[0];
  const float* g0 = guide + ((size_t)(b * 3 + 0) * H + y) * W;
  const float* g1 = guide + ((size_t)(b * 3 + 1) * H + y) * W;
  const float* g2 = guide + ((size_t)(b * 3 + 2) * H + y) * W;
  const float* yb = ybic + ((size_t)b * H + y) * W;
#pragma unroll
  for (int k = 0; k < 4; ++k) {
    int x = t + k * 256;
    float v = g0[x] + g1[x] + g2[x] + (yb[x] + sh);
    buf[brev10(x)] = make_float2(v, 0.0f);
  }
  __syncthreads();
  fft1024(buf, t, -1.0f);
  float2* out = A + ((size_t)b * H + y) * W;
#pragma unroll
  for (int k = 0; k < 4; ++k) { int x = t + k * 256; out[x] = buf[x]; }
}

// ---------------- complex transpose (per batch), LDS tiled ----------------
__global__ void k_transpose(const float2* __restrict__ in, float2* __restrict__ out) {
  __shared__ float2 tile[32][33];
  int b = blockIdx.z;
  int x0 = blockIdx.x * 32, y0 = blockIdx.y * 32;
  int tx = threadIdx.x, ty = threadIdx.y;  // (32,8)
  const float2* ip = in + (size_t)b * H * W;
  float2* op = out + (size_t)b * H * W;
#pragma unroll
  for (int k = 0; k < 4; ++k)
    tile[ty + k * 8][tx] = ip[(size_t)(y0 + ty + k * 8) * W + (x0 + tx)];
  __syncthreads();
#pragma unroll
  for (int k = 0; k < 4; ++k)
    op[(size_t)(x0 + ty + k * 8) * W + (y0 + tx)] = tile[tx][ty + k * 8];
}

// ---------------- column FFT + radial highpass mask + inverse column FFT ----------------
// Operates on transposed layout: row j holds original column j over k1.
__global__ void k_colfft_mask(float2* __restrict__ Bc) {
  __shared__ float2 bufA[1024];
  __shared__ float2 bufB[1024];
  int b = blockIdx.y, j = blockIdx.x, t = threadIdx.x;
  float2* row = Bc + ((size_t)b * W + j) * H;
#pragma unroll
  for (int k = 0; k < 4; ++k) { int i = t + k * 256; bufA[brev10(i)] = row[i]; }
  __syncthreads();
  fft1024(bufA, t, -1.0f);
  double xj = -1.0 + 2.0 * (double)j / 1023.0;  // linspace(-1,1,1024)[j]
  double xj2 = xj * xj;
#pragma unroll
  for (int k = 0; k < 4; ++k) {
    int i = t + k * 256;  // k1 index
    double yv = -1.0 + 2.0 * (double)i / 1023.0;
    float m = (xj2 + yv * yv > 0.25) ? 1.0f : 0.0f;  // sqrt(x^2+y^2) > 0.5
    float2 v = bufA[i];
    bufB[brev10(i)] = make_float2(v.x * m, v.y * m);
  }
  __syncthreads();
  fft1024(bufB, t, 1.0f);
#pragma unroll
  for (int k = 0; k < 4; ++k) { int i = t + k * 256; row[i] = bufB[i]; }
}

// ---------------- inverse row FFT, keep real part * scale -> er_sum ----------------
__global__ void k_rowfft_inv(const float2* __restrict__ A, float* __restrict__ er) {
  __shared__ float2 buf[1024];
  int b = blockIdx.y, y = blockIdx.x, t = threadIdx.x;
  const float2* in = A + ((size_t)b * H + y) * W;
#pragma unroll
  for (int k = 0; k < 4; ++k) { int i = t + k * 256; buf[brev10(i)] = in[i]; }
  __syncthreads();
  fft1024(buf, t, 1.0f);
  float* out = er + ((size_t)b * H + y) * W;
#pragma unroll
  for (int k = 0; k < 4; ++k) { int x = t + k * 256; out[x] = buf[x].x * FFT_SCALE; }
}

// ---------------- Perona-Malik coefficients cv, ch (zero-padded at y=1023 / x=1023) ----
__global__ void k_coeffs(const float* __restrict__ guide, const float* __restrict__ ybic,
                         const float* __restrict__ er, float* __restrict__ cv,
                         float* __restrict__ ch) {
  int b = blockIdx.y, y = blockIdx.x, t = threadIdx.x;
  const float* g = guide + (size_t)b * 3 * H * W;
  const float* yb = ybic + (size_t)b * H * W;
  const float* e = er + (size_t)b * H * W;
  float* cvp = cv + (size_t)b * H * W;
  float* chp = ch + (size_t)b * H * W;
  const size_t CH = (size_t)H * W;
  for (int k = 0; k < 4; ++k) {
    int x = t + k * 256;
    size_t idx = (size_t)y * W + x;
    float cvv = 0.0f;
    if (y < H - 1) {
      size_t idn = idx + W;
      float s = fabsf(g[idn] - g[idx]) + fabsf(g[CH + idn] - g[CH + idx]) +
                fabsf(g[2 * CH + idn] - g[2 * CH + idx]) + fabsf(yb[idn] - yb[idx]);
      s = (s + e[idn]) * 0.25f;  // mean over 4 channels (shift cancels in the img diff)
      cvv = 1.0f / (1.0f + (s * s) / KK);
    }
    cvp[idx] = cvv;
    float chv = 0.0f;
    if (x < W - 1) {
      size_t idr = idx + 1;
      float s = fabsf(g[idr] - g[idx]) + fabsf(g[CH + idr] - g[CH + idx]) +
                fabsf(g[2 * CH + idr] - g[2 * CH + idx]) + fabsf(yb[idr] - yb[idx]);
      s = (s + e[idr]) * 0.25f;
      chv = 1.0f / (1.0f + (s * s) / KK);
    }
    chp[idx] = chv;
  }
}

// ---------------- diffusion step (freq-smoothing branch is identity; see header note) ----
// Reads in[.] (+shift on iter 1) scaled by previous adjust ratio (nullptr on iter 1).
__global__ void k_diffuse(const float* __restrict__ in, const float* __restrict__ ratio,
                          const float* __restrict__ shiftp, int addShift,
                          const float* __restrict__ cv, const float* __restrict__ ch,
                          float* __restrict__ out) {
  int b = blockIdx.z, y = blockIdx.y;
  int x = blockIdx.x * 256 + threadIdx.x;
  float addv = addShift ? shiftp[0] : 0.0f;
  size_t base = (size_t)b * H * W;
  auto val = [&](int yy, int xx) -> float {
    float v = in[base + (size_t)yy * W + xx] + addv;
    if (ratio) v *= ratio[((size_t)b * SH + (yy >> 3)) * SW + (xx >> 3)];
    return v;
  };
  float c00 = val(y, x);
  float acc = c00;
  size_t idx = base + (size_t)y * W + x;
  if (y < H - 1) acc += LAM * cv[idx] * (val(y + 1, x) - c00);
  if (y > 0) acc -= LAM * cv[idx - W] * (c00 - val(y - 1, x));
  if (x < W - 1) acc += LAM * ch[idx] * (val(y, x + 1) - c00);
  if (x > 0) acc -= LAM * ch[idx - 1] * (c00 - val(y, x - 1));
  out[idx] = acc;
}

// ---------------- block mean 8x8 -> ratio_ss ----------------
__global__ void k_ratio(const float* __restrict__ img, const float* __restrict__ src,
                        const float* __restrict__ mask, const float* __restrict__ shiftp,
                        float* __restrict__ ratio) {
  int b = blockIdx.z, by = blockIdx.y, t = threadIdx.x;
  int x = blockIdx.x * 256 + t;
  size_t base = ((size_t)b * H + (size_t)by * 8) * W + x;
  float s = 0.0f;
#pragma unroll
  for (int r = 0; r < 8; ++r) s += img[base + (size_t)r * W];
  s += __shfl_xor(s, 1);
  s += __shfl_xor(s, 2);
  s += __shfl_xor(s, 4);
  if ((t & 7) == 0) {
    size_t si = ((size_t)b * SH + by) * SW + (x >> 3);
    float mean = s * (1.0f / 64.0f);
    ratio[si] = (mask[si] < 0.5f) ? 1.0f : (src[si] + shiftp[0]) / (mean + 1e-8f);
  }
}

// ---------------- out = d8 * r8 - shift (in place on d_out) ----------------
__global__ void k_final(float* __restrict__ io, const float* __restrict__ ratio,
                        const float* __restrict__ shiftp) {
  size_t i = (size_t)blockIdx.x * 256 + threadIdx.x;
  int b = (int)(i >> 20);
  int rem = (int)(i & 1048575);
  int y = rem >> 10, x = rem & 1023;
  float r = ratio[((size_t)b * SH + (y >> 3)) * SW + (x >> 3)];
  io[i] = io[i] * r - shiftp[0];
}

}  // namespace

extern "C" void kernel_launch(void* const* d_in, const int* in_sizes, int n_in, void* d_out,
                              int out_size, void* d_ws, size_t ws_size, hipStream_t stream) {
  (void)in_sizes; (void)n_in; (void)out_size; (void)ws_size;
  const float* guide = (const float*)d_in[0];
  const float* source = (const float*)d_in[1];
  const float* mask = (const float*)d_in[2];
  const float* ybic = (const float*)d_in[3];
  float* out = (float*)d_out;

  char* ws = (char*)d_ws;
  float2* A = (float2*)ws;                                   // 32 MB complex
  float2* Bc = (float2*)(ws + (size_t)32 * 1024 * 1024);     // 32 MB complex
  // after the FFT chain A/Bc are dead -> alias:
  float* cv = (float*)ws;                                    // 16 MB
  float* ch = (float*)(ws + (size_t)16 * 1024 * 1024);       // 16 MB
  float* er = (float*)(ws + (size_t)32 * 1024 * 1024);       // 16 MB (low half of Bc)
  float* itmp = (float*)(ws + (size_t)48 * 1024 * 1024);     // 16 MB (high half of Bc)
  float* shiftp = (float*)(ws + (size_t)64 * 1024 * 1024);   // 1 float
  float* ratio = shiftp + 64;                                // 256 KB

  k_shift<<<1, 256, 0, stream>>>(source, shiftp);

  // er_sum = real(ifft2(fft2(sum_c feats_c) * hf_mask))  (linearity over channels)
  k_rowfft_fwd<<<dim3(H, NB), 256, 0, stream>>>(guide, ybic, shiftp, A);
  dim3 gT(W / 32, H / 32, NB), bT(32, 8);
  k_transpose<<<gT, bT, 0, stream>>>(A, Bc);
  k_colfft_mask<<<dim3(W, NB), 256, 0, stream>>>(Bc);
  k_transpose<<<gT, bT, 0, stream>>>(Bc, A);
  k_rowfft_inv<<<dim3(H, NB), 256, 0, stream>>>(A, er);

  k_coeffs<<<dim3(H, NB), 256, 0, stream>>>(guide, ybic, er, cv, ch);

  // 8 x { diffuse (prev ratio fused on load) ; block-mean ratio }
  const float* cur = ybic;
  float* bufs[2] = {itmp, out};
  const float* rprev = nullptr;
  for (int it = 0; it < NPRE_IT; ++it) {
    float* dst = bufs[it & 1];
    k_diffuse<<<dim3(W / 256, H, NB), 256, 0, stream>>>(cur, rprev, shiftp, it == 0 ? 1 : 0,
                                                        cv, ch, dst);
    k_ratio<<<dim3(W / 256, SH, NB), 256, 0, stream>>>(dst, source, mask, shiftp, ratio);
    cur = dst;
    rprev = ratio;
  }
  // d8 lives in d_out (even number of ping-pongs); apply last ratio and subtract shift.
  k_final<<<dim3(NB * H * W / 256), 256, 0, stream>>>(out, ratio, shiftp);
}

// Round 4
// 504.361 us; speedup vs baseline: 1.1169x; 1.1169x over previous
//
#include <hip/hip_runtime.h>

namespace {

constexpr int H = 1024, W = 1024, NB = 4;
constexpr int SH = 128, SW = 128;
constexpr int NPRE_IT = 8;
constexpr float LAM = 0.24f;
constexpr float KK = 0.03f * 0.03f;
constexpr float DEPS_V = 0.1f;
constexpr float FFT_SCALE = 1.0f / (1024.0f * 1024.0f);  // ortho fwd+inv combined

__device__ __forceinline__ int brev10(int i) { return (int)(__brev((unsigned)i) >> 22); }
// LDS pad: physical index for butterfly buffer, breaks power-of-2 stride conflicts
__device__ __forceinline__ int phys(int i) { return i + (i >> 5); }

// Skip predicate for column k2 (raw DFT bin): mask is identically 1 there.
// MUST be bit-identical everywhere it is evaluated.
__device__ __forceinline__ bool col_skip(int k2) {
  double xj = -1.0 + 2.0 * (double)k2 / 1023.0;
  return xj * xj > 0.25;
}

// ---------------- min(source): 2-stage parallel reduction ----------------
__global__ void k_shift_part(const float* __restrict__ src, float* __restrict__ partial) {
  int t = threadIdx.x;
  int b0 = blockIdx.x * 1024;
  float m = fminf(fminf(src[b0 + t], src[b0 + t + 256]),
                  fminf(src[b0 + t + 512], src[b0 + t + 768]));
  for (int o = 32; o > 0; o >>= 1) m = fminf(m, __shfl_xor(m, o));
  __shared__ float sm[4];
  if ((t & 63) == 0) sm[t >> 6] = m;
  __syncthreads();
  if (t == 0) partial[blockIdx.x] = fminf(fminf(sm[0], sm[1]), fminf(sm[2], sm[3]));
}

__global__ void k_shift_fin(const float* __restrict__ partial, float* __restrict__ shiftp) {
  int t = threadIdx.x;  // 64 threads
  float m = partial[t];
  for (int o = 32; o > 0; o >>= 1) m = fminf(m, __shfl_xor(m, o));
  if (t == 0) shiftp[0] = (m <= DEPS_V) ? DEPS_V : 0.0f;
}

// ---------------- FFT helpers: 1024-pt radix-2, LDS twiddle table ----------------
// twid[k] = e^{-i*pi*k/512} = W_1024^k
__device__ __forceinline__ void init_twid(float2* tw, int t) {
  for (int k = t; k < 512; k += 256) {
    float sn, cs;
    sincospif((float)k * (1.0f / 512.0f), &sn, &cs);
    tw[k] = make_float2(cs, -sn);
  }
}

// DIF forward: natural-order input -> bit-reversed output. 256 threads.
__device__ void fft_dif(float2* buf, const float2* tw, int t) {
  for (int s = 10; s >= 1; --s) {
    int half = 1 << (s - 1);
#pragma unroll
    for (int jj = 0; jj < 2; ++jj) {
      int j = t + jj * 256;
      int pos = j & (half - 1);
      int i1 = ((j >> (s - 1)) << s) + pos;
      int i2 = i1 + half;
      float2 u = buf[phys(i1)], v = buf[phys(i2)];
      float2 w = tw[pos << (10 - s)];
      float dx = u.x - v.x, dy = u.y - v.y;
      buf[phys(i1)] = make_float2(u.x + v.x, u.y + v.y);
      buf[phys(i2)] = make_float2(dx * w.x - dy * w.y, dx * w.y + dy * w.x);
    }
    __syncthreads();
  }
}

// DIT inverse (unnormalized): bit-reversed input -> natural-order output.
__device__ void fft_dit_inv(float2* buf, const float2* tw, int t) {
  for (int s = 1; s <= 10; ++s) {
    int half = 1 << (s - 1);
#pragma unroll
    for (int jj = 0; jj < 2; ++jj) {
      int j = t + jj * 256;
      int pos = j & (half - 1);
      int i1 = ((j >> (s - 1)) << s) + pos;
      int i2 = i1 + half;
      float2 u = buf[phys(i1)], v = buf[phys(i2)];
      float2 w = tw[pos << (10 - s)];  // stored e^{-it}; inverse uses conj
      float vr = v.x * w.x + v.y * w.y;
      float vi = v.y * w.x - v.x * w.y;
      buf[phys(i1)] = make_float2(u.x + vr, u.y + vi);
      buf[phys(i2)] = make_float2(u.x - vr, u.y - vi);
    }
    __syncthreads();
  }
}

// ---------------- forward row FFT of S = g0+g1+g2+(ybic+shift) ----------------
// Output position p holds F(y, k2=brev10(p)).
__global__ void k_rowfft_fwd(const float* __restrict__ guide, const float* __restrict__ ybic,
                             const float* __restrict__ shiftp, float2* __restrict__ A) {
  __shared__ float2 buf[1056];
  __shared__ float2 tw[512];
  int b = blockIdx.y, y = blockIdx.x, t = threadIdx.x;
  init_twid(tw, t);
  float sh = shiftp[0];
  const float* g0 = guide + ((size_t)(b * 3 + 0) * H + y) * W;
  const float* g1 = guide + ((size_t)(b * 3 + 1) * H + y) * W;
  const float* g2 = guide + ((size_t)(b * 3 + 2) * H + y) * W;
  const float* yb = ybic + ((size_t)b * H + y) * W;
#pragma unroll
  for (int k = 0; k < 4; ++k) {
    int x = t + k * 256;
    float v = g0[x] + g1[x] + g2[x] + (yb[x] + sh);
    buf[phys(x)] = make_float2(v, 0.0f);
  }
  __syncthreads();
  fft_dif(buf, tw, t);
  float2* out = A + ((size_t)b * H + y) * W;
#pragma unroll
  for (int k = 0; k < 4; ++k) { int x = t + k * 256; out[x] = buf[phys(x)]; }
}

// ---------------- complex transpose (per batch), LDS tiled ----------------
__global__ void k_transpose(const float2* __restrict__ in, float2* __restrict__ out) {
  __shared__ float2 tile[32][33];
  int b = blockIdx.z;
  int x0 = blockIdx.x * 32, y0 = blockIdx.y * 32;
  int tx = threadIdx.x, ty = threadIdx.y;  // (32,8)
  const float2* ip = in + (size_t)b * H * W;
  float2* op = out + (size_t)b * H * W;
#pragma unroll
  for (int k = 0; k < 4; ++k)
    tile[ty + k * 8][tx] = ip[(size_t)(y0 + ty + k * 8) * W + (x0 + tx)];
  __syncthreads();
#pragma unroll
  for (int k = 0; k < 4; ++k)
    op[(size_t)(x0 + ty + k * 8) * W + (y0 + tx)] = tile[tx][ty + k * 8];
}

// ---------------- column FFT + radial highpass mask + inverse column FFT ----------------
// Bc row j holds original freq column k2=brev10(j) over spatial y.
// Columns with xj^2 > 0.25: mask all-ones (yv^2 >= (1/1023)^2 > 0) -> fwd+inv would be
// 1024 * identity. We skip them entirely here (no memory traffic) and compensate the
// missing x1024 in k_rowfft_inv's load (exact power-of-two scale, bit-identical predicate).
__global__ void k_colfft_mask(float2* __restrict__ Bc) {
  int b = blockIdx.y, j = blockIdx.x, t = threadIdx.x;
  int k2 = brev10(j);
  if (col_skip(k2)) return;  // pass-through column, compensated later
  double xj = -1.0 + 2.0 * (double)k2 / 1023.0;
  double xj2 = xj * xj;
  __shared__ float2 buf[1056];
  __shared__ float2 tw[512];
  init_twid(tw, t);
  float2* row = Bc + ((size_t)b * W + j) * H;
#pragma unroll
  for (int k = 0; k < 4; ++k) { int i = t + k * 256; buf[phys(i)] = row[i]; }
  __syncthreads();
  fft_dif(buf, tw, t);
#pragma unroll
  for (int k = 0; k < 4; ++k) {
    int q = t + k * 256;          // position after DIF
    int i = brev10(q);            // k1 index
    double yv = -1.0 + 2.0 * (double)i / 1023.0;
    if (xj2 + yv * yv <= 0.25) buf[phys(q)] = make_float2(0.0f, 0.0f);
  }
  __syncthreads();
  fft_dit_inv(buf, tw, t);
#pragma unroll
  for (int k = 0; k < 4; ++k) { int i = t + k * 256; row[i] = buf[phys(i)]; }
}

// ---------------- inverse row FFT, keep real part * scale -> er_sum ----------------
// Skipped columns missed the unnormalized fwd+inv y-transform pair (= x1024); apply it here.
__global__ void k_rowfft_inv(const float2* __restrict__ A, float* __restrict__ er) {
  __shared__ float2 buf[1056];
  __shared__ float2 tw[512];
  int b = blockIdx.y, y = blockIdx.x, t = threadIdx.x;
  init_twid(tw, t);
  const float2* in = A + ((size_t)b * H + y) * W;
#pragma unroll
  for (int k = 0; k < 4; ++k) {
    int j = t + k * 256;
    float2 v = in[j];
    if (col_skip(brev10(j))) { v.x *= 1024.0f; v.y *= 1024.0f; }
    buf[phys(j)] = v;
  }
  __syncthreads();
  fft_dit_inv(buf, tw, t);
  float* out = er + ((size_t)b * H + y) * W;
#pragma unroll
  for (int k = 0; k < 4; ++k) { int x = t + k * 256; out[x] = buf[phys(x)].x * FFT_SCALE; }
}

// ---------------- Perona-Malik coefficients cv, ch ----------------
__global__ void k_coeffs(const float* __restrict__ guide, const float* __restrict__ ybic,
                         const float* __restrict__ er, float* __restrict__ cv,
                         float* __restrict__ ch) {
  int b = blockIdx.y, y = blockIdx.x, t = threadIdx.x;
  const float* g = guide + (size_t)b * 3 * H * W;
  const float* yb = ybic + (size_t)b * H * W;
  const float* e = er + (size_t)b * H * W;
  float* cvp = cv + (size_t)b * H * W;
  float* chp = ch + (size_t)b * H * W;
  const size_t CH = (size_t)H * W;
  for (int k = 0; k < 4; ++k) {
    int x = t + k * 256;
    size_t idx = (size_t)y * W + x;
    float cvv = 0.0f;
    if (y < H - 1) {
      size_t idn = idx + W;
      float s = fabsf(g[idn] - g[idx]) + fabsf(g[CH + idn] - g[CH + idx]) +
                fabsf(g[2 * CH + idn] - g[2 * CH + idx]) + fabsf(yb[idn] - yb[idx]);
      s = (s + e[idn]) * 0.25f;  // channel mean (shift cancels in img diff)
      cvv = 1.0f / (1.0f + (s * s) / KK);
    }
    cvp[idx] = cvv;
    float chv = 0.0f;
    if (x < W - 1) {
      size_t idr = idx + 1;
      float s = fabsf(g[idr] - g[idx]) + fabsf(g[CH + idr] - g[CH + idx]) +
                fabsf(g[2 * CH + idr] - g[2 * CH + idx]) + fabsf(yb[idr] - yb[idx]);
      s = (s + e[idr]) * 0.25f;
      chv = 1.0f / (1.0f + (s * s) / KK);
    }
    chp[idx] = chv;
  }
}

// ---------------- fused diffuse + 8x8 block-mean ratio ----------------
// Block (32,8) covers a 32x8 tile aligned to the 8x8 pooling grid (4 subtiles).
// Previous adjust ratio applied on load; freq-smoothing branch is identity (sigma=0.1).
__global__ void k_diffuse_ratio(const float* __restrict__ in, const float* __restrict__ ratio_in,
                                const float* __restrict__ shiftp, int addShift,
                                const float* __restrict__ cv, const float* __restrict__ ch,
                                const float* __restrict__ src, const float* __restrict__ mask,
                                float* __restrict__ out, float* __restrict__ ratio_out) {
  int b = blockIdx.z;
  int tx = threadIdx.x, ty = threadIdx.y;
  int x = blockIdx.x * 32 + tx;
  int y = blockIdx.y * 8 + ty;
  float addv = addShift ? shiftp[0] : 0.0f;
  size_t base = (size_t)b * H * W;
  const float* rb = ratio_in ? ratio_in + (size_t)b * SH * SW : nullptr;
  auto val = [&](int yy, int xx) -> float {
    float v = in[base + (size_t)yy * W + xx] + addv;
    if (rb) v *= rb[(size_t)(yy >> 3) * SW + (xx >> 3)];
    return v;
  };
  float c00 = val(y, x);
  float acc = c00;
  size_t idx = base + (size_t)y * W + x;
  if (y < H - 1) acc += LAM * cv[idx] * (val(y + 1, x) - c00);
  if (y > 0) acc -= LAM * cv[idx - W] * (c00 - val(y - 1, x));
  if (x < W - 1) acc += LAM * ch[idx] * (val(y, x + 1) - c00);
  if (x > 0) acc -= LAM * ch[idx - 1] * (c00 - val(y, x - 1));
  out[idx] = acc;

  __shared__ float sd[8][33];
  sd[ty][tx] = acc;
  __syncthreads();
  if (ty == 0) {  // lanes 0..31 of wave 0
    float s = 0.0f;
#pragma unroll
    for (int r = 0; r < 8; ++r) s += sd[r][tx];
    s += __shfl_xor(s, 1);
    s += __shfl_xor(s, 2);
    s += __shfl_xor(s, 4);
    if ((tx & 7) == 0) {
      size_t si = ((size_t)b * SH + blockIdx.y) * SW + ((blockIdx.x * 32 + tx) >> 3);
      float mean = s * (1.0f / 64.0f);
      ratio_out[si] = (mask[si] < 0.5f) ? 1.0f : (src[si] + shiftp[0]) / (mean + 1e-8f);
    }
  }
}

// ---------------- out = d8 * r8 - shift (in place on d_out) ----------------
__global__ void k_final(float* __restrict__ io, const float* __restrict__ ratio,
                        const float* __restrict__ shiftp) {
  size_t i = (size_t)blockIdx.x * 256 + threadIdx.x;
  int b = (int)(i >> 20);
  int rem = (int)(i & 1048575);
  int y = rem >> 10, x = rem & 1023;
  float r = ratio[((size_t)b * SH + (y >> 3)) * SW + (x >> 3)];
  io[i] = io[i] * r - shiftp[0];
}

}  // namespace

extern "C" void kernel_launch(void* const* d_in, const int* in_sizes, int n_in, void* d_out,
                              int out_size, void* d_ws, size_t ws_size, hipStream_t stream) {
  (void)in_sizes; (void)n_in; (void)out_size; (void)ws_size;
  const float* guide = (const float*)d_in[0];
  const float* source = (const float*)d_in[1];
  const float* mask = (const float*)d_in[2];
  const float* ybic = (const float*)d_in[3];
  float* out = (float*)d_out;

  // Workspace packing — max offset 64MB + 512B, within the footprint proven safe in R1.
  char* ws = (char*)d_ws;
  float2* A = (float2*)ws;                                  // [0,32MB) complex
  float2* Bc = (float2*)(ws + (size_t)32 * 1024 * 1024);    // [32,64MB) complex
  // after the FFT chain A/Bc are dead -> alias:
  float* cv = (float*)ws;                                   // [0,16MB)
  float* ch = (float*)(ws + (size_t)16 * 1024 * 1024);      // [16,32MB)
  float* er = (float*)(ws + (size_t)32 * 1024 * 1024);      // [32,48MB)
  float* itmp = (float*)(ws + (size_t)48 * 1024 * 1024);    // [48,64MB)
  // er is dead after k_coeffs; ratios live there (first write is in iter 0, post-coeffs)
  float* ratioA = er;                                       // 256KB
  float* ratioB = er + (size_t)NB * SH * SW;                // 256KB
  float* shiftp = (float*)(ws + (size_t)64 * 1024 * 1024);  // 1 float
  float* partial = shiftp + 64;                             // 64 floats

  k_shift_part<<<64, 256, 0, stream>>>(source, partial);
  k_shift_fin<<<1, 64, 0, stream>>>(partial, shiftp);

  // er_sum = real(ifft2(fft2(sum_c feats_c) * hf_mask))  (linearity over channels)
  k_rowfft_fwd<<<dim3(H, NB), 256, 0, stream>>>(guide, ybic, shiftp, A);
  dim3 gT(W / 32, H / 32, NB), bT(32, 8);
  k_transpose<<<gT, bT, 0, stream>>>(A, Bc);
  k_colfft_mask<<<dim3(W, NB), 256, 0, stream>>>(Bc);
  k_transpose<<<gT, bT, 0, stream>>>(Bc, A);
  k_rowfft_inv<<<dim3(H, NB), 256, 0, stream>>>(A, er);

  k_coeffs<<<dim3(H, NB), 256, 0, stream>>>(guide, ybic, er, cv, ch);

  // 8 x fused { diffuse (prev ratio on load) ; block-mean ratio } with ratio ping-pong
  const float* cur = ybic;
  float* bufs[2] = {itmp, out};
  float* ratios[2] = {ratioA, ratioB};
  const float* rprev = nullptr;
  float* rlast = nullptr;
  for (int it = 0; it < NPRE_IT; ++it) {
    float* dst = bufs[it & 1];
    float* rout = ratios[it & 1];
    k_diffuse_ratio<<<dim3(W / 32, H / 8, NB), dim3(32, 8), 0, stream>>>(
        cur, rprev, shiftp, it == 0 ? 1 : 0, cv, ch, source, mask, dst, rout);
    cur = dst;
    rprev = rout;
    rlast = rout;
  }
  // d8 lives in d_out (even number of ping-pongs); apply last ratio and subtract shift.
  k_final<<<dim3(NB * H * W / 256), 256, 0, stream>>>(out, rlast, shiftp);
}

// Round 5
// 463.113 us; speedup vs baseline: 1.2164x; 1.0891x over previous
//
#include <hip/hip_runtime.h>
#include <hip/hip_fp16.h>

namespace {

constexpr int H = 1024, W = 1024, NB = 4;
constexpr int SH = 128, SW = 128;
constexpr int NPRE_IT = 8;
constexpr float LAM = 0.24f;
constexpr float KK = 0.03f * 0.03f;
constexpr float DEPS_V = 0.1f;
constexpr float FFT_SCALE = 1.0f / (1024.0f * 1024.0f);  // ortho fwd+inv combined
// Processed (masked) columns: |x(k2)| <= 0.5  <=>  k2 in [256, 768). Margins to the
// 0.25 boundary are ~1.5e-3 (k2=255: x^2=0.2515, 256: 0.2495) >> any fp error.
constexpr int COL_LO = 256, COL_HI = 768, NCOL = COL_HI - COL_LO;  // 512

__device__ __forceinline__ float2 cadd(float2 a, float2 b) { return make_float2(a.x + b.x, a.y + b.y); }
__device__ __forceinline__ float2 csub(float2 a, float2 b) { return make_float2(a.x - b.x, a.y - b.y); }
__device__ __forceinline__ float2 cmul(float2 a, float2 b) {
  return make_float2(a.x * b.x - a.y * b.y, a.x * b.y + a.y * b.x);
}
// LDS physical index: +1 float2 skew every 16 elements -> uniform bank spread for all
// Stockham stage strides (verified residue-uniform for Ns=1,4,16,64 writes and stride-256 reads).
__device__ __forceinline__ int phys2(int e) { return e + (e >> 4); }

// ---------------- min(source): 2-stage parallel reduction ----------------
__global__ void k_shift_part(const float* __restrict__ src, float* __restrict__ partial) {
  int t = threadIdx.x;
  int b0 = blockIdx.x * 1024;
  float m = fminf(fminf(src[b0 + t], src[b0 + t + 256]),
                  fminf(src[b0 + t + 512], src[b0 + t + 768]));
  for (int o = 32; o > 0; o >>= 1) m = fminf(m, __shfl_xor(m, o));
  __shared__ float sm[4];
  if ((t & 63) == 0) sm[t >> 6] = m;
  __syncthreads();
  if (t == 0) partial[blockIdx.x] = fminf(fminf(sm[0], sm[1]), fminf(sm[2], sm[3]));
}

__global__ void k_shift_fin(const float* __restrict__ partial, float* __restrict__ shiftp) {
  int t = threadIdx.x;  // 64 threads
  float m = partial[t];
  for (int o = 32; o > 0; o >>= 1) m = fminf(m, __shfl_xor(m, o));
  if (t == 0) shiftp[0] = (m <= DEPS_V) ? DEPS_V : 0.0f;
}

// ---------------- Stockham radix-4 1024-pt FFT: natural in -> natural out ----------------
// 256 threads, 4 elements/thread at stride 256, 5 stages (Ns=1,4,16,64,256), double-buffered
// LDS, 4 barriers per transform. Verified by hand at N=4 and N=16 (butterfly + (0,2,1,3)
// store order + twiddle w^k, w = exp(sign*2*pi*i*(j%Ns)/(4Ns))).
template <int NS, bool INV>
__device__ __forceinline__ void r4_butterfly(float2 v[4], int j, float2 r[4]) {
  if (NS > 1) {
    int p = j & (NS - 1);
    float sn, cs;
    sincospif((INV ? 1.0f : -1.0f) * (float)p * (1.0f / (float)(2 * NS)), &sn, &cs);
    float2 w1 = make_float2(cs, sn);
    float2 w2 = cmul(w1, w1);
    float2 w3 = cmul(w2, w1);
    v[1] = cmul(v[1], w1);
    v[2] = cmul(v[2], w2);
    v[3] = cmul(v[3], w3);
  }
  float2 a0 = cadd(v[0], v[2]), a2 = csub(v[0], v[2]);
  float2 a1 = cadd(v[1], v[3]), a3 = csub(v[1], v[3]);
  a3 = INV ? make_float2(-a3.y, a3.x) : make_float2(a3.y, -a3.x);  // * (+/- i)
  r[0] = cadd(a0, a1);
  r[2] = csub(a0, a1);
  r[1] = cadd(a2, a3);
  r[3] = csub(a2, a3);
}

template <int NS, bool INV>
__device__ __forceinline__ void r4_stage_lds(float2 v[4], float2* dst, int j) {
  float2 r[4];
  r4_butterfly<NS, INV>(v, j, r);
  int p = j & (NS - 1);
  int base = ((j - p) << 2) + p;  // (j/Ns)*4Ns + p
#pragma unroll
  for (int k = 0; k < 4; ++k) dst[phys2(base + k * NS)] = r[k];
}

__device__ __forceinline__ void lds_load4(const float2* src, float2 v[4], int j) {
#pragma unroll
  for (int k = 0; k < 4; ++k) v[k] = src[phys2(j + k * 256)];
}

// In: v[k] = x[j + 256k] (natural). Out: v[k] = X[j + 256k] (natural).
template <bool INV>
__device__ void fft1024(float2 v[4], float2* b0, float2* b1, int j) {
  r4_stage_lds<1, INV>(v, b0, j);
  __syncthreads();
  lds_load4(b0, v, j);
  r4_stage_lds<4, INV>(v, b1, j);
  __syncthreads();
  lds_load4(b1, v, j);
  r4_stage_lds<16, INV>(v, b0, j);
  __syncthreads();
  lds_load4(b0, v, j);
  r4_stage_lds<64, INV>(v, b1, j);
  __syncthreads();
  lds_load4(b1, v, j);
  float2 r[4];
  r4_butterfly<256, INV>(v, j, r);  // final stage: idxD=j -> r[k] is bin j+256k
#pragma unroll
  for (int k = 0; k < 4; ++k) v[k] = r[k];
}

// ---------------- forward row FFT of S = g0+g1+g2+(ybic+shift) ----------------
__global__ void k_rowfft_fwd(const float* __restrict__ guide, const float* __restrict__ ybic,
                             const float* __restrict__ shiftp, float2* __restrict__ A) {
  __shared__ float2 b0[1088], b1[1088];
  int b = blockIdx.y, y = blockIdx.x, j = threadIdx.x;
  float sh = shiftp[0];
  const float* g0 = guide + ((size_t)(b * 3 + 0) * H + y) * W;
  const float* g1 = guide + ((size_t)(b * 3 + 1) * H + y) * W;
  const float* g2 = guide + ((size_t)(b * 3 + 2) * H + y) * W;
  const float* yb = ybic + ((size_t)b * H + y) * W;
  float2 v[4];
#pragma unroll
  for (int k = 0; k < 4; ++k) {
    int x = j + k * 256;
    v[k] = make_float2(g0[x] + g1[x] + g2[x] + (yb[x] + sh), 0.0f);
  }
  fft1024<false>(v, b0, b1, j);
  float2* out = A + ((size_t)b * H + y) * W;
#pragma unroll
  for (int k = 0; k < 4; ++k) out[j + k * 256] = v[k];
}

// ---------------- half-width transposes: only columns [256,768) round-trip ----------------
__global__ void k_transpose_fwd(const float2* __restrict__ A, float2* __restrict__ Bc) {
  __shared__ float2 tile[32][33];
  int b = blockIdx.z;
  int c0 = blockIdx.x * 32;  // 0..480 over NCOL
  int y0 = blockIdx.y * 32;
  const float2* ip = A + (size_t)b * H * W;
  float2* op = Bc + (size_t)b * NCOL * H;
#pragma unroll
  for (int k = 0; k < 4; ++k)
    tile[threadIdx.y + k * 8][threadIdx.x] =
        ip[(size_t)(y0 + threadIdx.y + k * 8) * W + (COL_LO + c0 + threadIdx.x)];
  __syncthreads();
#pragma unroll
  for (int k = 0; k < 4; ++k)
    op[(size_t)(c0 + threadIdx.y + k * 8) * H + (y0 + threadIdx.x)] =
        tile[threadIdx.x][threadIdx.y + k * 8];
}

__global__ void k_transpose_bwd(const float2* __restrict__ Bc, float2* __restrict__ A) {
  __shared__ float2 tile[32][33];
  int b = blockIdx.z;
  int c0 = blockIdx.x * 32;
  int y0 = blockIdx.y * 32;
  const float2* ip = Bc + (size_t)b * NCOL * H;
  float2* op = A + (size_t)b * H * W;
#pragma unroll
  for (int k = 0; k < 4; ++k)
    tile[threadIdx.y + k * 8][threadIdx.x] =
        ip[(size_t)(c0 + threadIdx.y + k * 8) * H + (y0 + threadIdx.x)];
  __syncthreads();
#pragma unroll
  for (int k = 0; k < 4; ++k)
    op[(size_t)(y0 + threadIdx.y + k * 8) * W + (COL_LO + c0 + threadIdx.x)] =
        tile[threadIdx.x][threadIdx.y + k * 8];
}

// ---------------- column FFT + radial highpass mask + inverse column FFT ----------------
// Bc row r holds freq column k2 = COL_LO + r over spatial y. All columns here are processed.
__global__ void k_colfft_mask(float2* __restrict__ Bc) {
  __shared__ float2 b0[1088], b1[1088];
  int b = blockIdx.y, r = blockIdx.x, j = threadIdx.x;
  int k2 = COL_LO + r;
  double xj = -1.0 + 2.0 * (double)k2 / 1023.0;
  double xj2 = xj * xj;
  float2* row = Bc + ((size_t)b * NCOL + r) * H;
  float2 v[4];
#pragma unroll
  for (int k = 0; k < 4; ++k) v[k] = row[j + k * 256];
  fft1024<false>(v, b0, b1, j);
#pragma unroll
  for (int k = 0; k < 4; ++k) {
    int i = j + k * 256;  // k1 bin (natural order)
    double yv = -1.0 + 2.0 * (double)i / 1023.0;
    if (xj2 + yv * yv <= 0.25) v[k] = make_float2(0.0f, 0.0f);
  }
  fft1024<true>(v, b0, b1, j);
#pragma unroll
  for (int k = 0; k < 4; ++k) row[j + k * 256] = v[k];
}

// ---------------- inverse row FFT, keep real part * scale -> er_sum ----------------
// Skipped columns (bins [0,256) and [768,1024) = v[0], v[3]) missed the unnormalized
// fwd+inv y-pair (= x1024); compensate here (exact pow2).
__global__ void k_rowfft_inv(const float2* __restrict__ A, float* __restrict__ er) {
  __shared__ float2 b0[1088], b1[1088];
  int b = blockIdx.y, y = blockIdx.x, j = threadIdx.x;
  const float2* in = A + ((size_t)b * H + y) * W;
  float2 v[4];
#pragma unroll
  for (int k = 0; k < 4; ++k) v[k] = in[j + k * 256];
  v[0].x *= 1024.0f; v[0].y *= 1024.0f;
  v[3].x *= 1024.0f; v[3].y *= 1024.0f;
  fft1024<true>(v, b0, b1, j);
  float* out = er + ((size_t)b * H + y) * W;
#pragma unroll
  for (int k = 0; k < 4; ++k) out[j + k * 256] = v[k].x * FFT_SCALE;
}

// ---------------- Perona-Malik coefficients, packed half2 {cv, ch} ----------------
__global__ void k_coeffs(const float* __restrict__ guide, const float* __restrict__ ybic,
                         const float* __restrict__ er, __half2* __restrict__ cvh) {
  int b = blockIdx.y, y = blockIdx.x, t = threadIdx.x;
  const float* g = guide + (size_t)b * 3 * H * W;
  const float* yb = ybic + (size_t)b * H * W;
  const float* e = er + (size_t)b * H * W;
  __half2* cp = cvh + (size_t)b * H * W;
  const size_t CH = (size_t)H * W;
  for (int k = 0; k < 4; ++k) {
    int x = t + k * 256;
    size_t idx = (size_t)y * W + x;
    float cvv = 0.0f;
    if (y < H - 1) {
      size_t idn = idx + W;
      float s = fabsf(g[idn] - g[idx]) + fabsf(g[CH + idn] - g[CH + idx]) +
                fabsf(g[2 * CH + idn] - g[2 * CH + idx]) + fabsf(yb[idn] - yb[idx]);
      s = (s + e[idn]) * 0.25f;  // channel mean (shift cancels in img diff)
      cvv = 1.0f / (1.0f + (s * s) / KK);
    }
    float chv = 0.0f;
    if (x < W - 1) {
      size_t idr = idx + 1;
      float s = fabsf(g[idr] - g[idx]) + fabsf(g[CH + idr] - g[CH + idx]) +
                fabsf(g[2 * CH + idr] - g[2 * CH + idx]) + fabsf(yb[idr] - yb[idx]);
      s = (s + e[idr]) * 0.25f;
      chv = 1.0f / (1.0f + (s * s) / KK);
    }
    cp[idx] = __floats2half2_rn(cvv, chv);
  }
}

// ---------------- fused diffuse + 8x8 block-mean ratio ----------------
__global__ void k_diffuse_ratio(const float* __restrict__ in, const float* __restrict__ ratio_in,
                                const float* __restrict__ shiftp, int addShift,
                                const __half2* __restrict__ cvh, const float* __restrict__ src,
                                const float* __restrict__ mask, float* __restrict__ out,
                                float* __restrict__ ratio_out) {
  int b = blockIdx.z;
  int tx = threadIdx.x, ty = threadIdx.y;
  int x = blockIdx.x * 32 + tx;
  int y = blockIdx.y * 8 + ty;
  float addv = addShift ? shiftp[0] : 0.0f;
  size_t base = (size_t)b * H * W;
  const __half2* cp = cvh + base;
  const float* rb = ratio_in ? ratio_in + (size_t)b * SH * SW : nullptr;
  auto val = [&](int yy, int xx) -> float {
    float v = in[base + (size_t)yy * W + xx] + addv;
    if (rb) v *= rb[(size_t)(yy >> 3) * SW + (xx >> 3)];
    return v;
  };
  float c00 = val(y, x);
  float acc = c00;
  size_t idx = base + (size_t)y * W + x;
  size_t lidx = (size_t)y * W + x;
  float2 cc = __half22float2(cp[lidx]);  // {cv(y,x), ch(y,x)}
  if (y < H - 1) acc += LAM * cc.x * (val(y + 1, x) - c00);
  if (y > 0) acc -= LAM * __half2float(cp[lidx - W].x) * (c00 - val(y - 1, x));
  if (x < W - 1) acc += LAM * cc.y * (val(y, x + 1) - c00);
  if (x > 0) acc -= LAM * __half2float(cp[lidx - 1].y) * (c00 - val(y, x - 1));
  out[idx] = acc;

  __shared__ float sd[8][33];
  sd[ty][tx] = acc;
  __syncthreads();
  if (ty == 0) {  // lanes 0..31 of wave 0
    float s = 0.0f;
#pragma unroll
    for (int r = 0; r < 8; ++r) s += sd[r][tx];
    s += __shfl_xor(s, 1);
    s += __shfl_xor(s, 2);
    s += __shfl_xor(s, 4);
    if ((tx & 7) == 0) {
      size_t si = ((size_t)b * SH + blockIdx.y) * SW + ((blockIdx.x * 32 + tx) >> 3);
      float mean = s * (1.0f / 64.0f);
      ratio_out[si] = (mask[si] < 0.5f) ? 1.0f : (src[si] + shiftp[0]) / (mean + 1e-8f);
    }
  }
}

// ---------------- out = d8 * r8 - shift (in place on d_out) ----------------
__global__ void k_final(float* __restrict__ io, const float* __restrict__ ratio,
                        const float* __restrict__ shiftp) {
  size_t i = (size_t)blockIdx.x * 256 + threadIdx.x;
  int b = (int)(i >> 20);
  int rem = (int)(i & 1048575);
  int y = rem >> 10, x = rem & 1023;
  float r = ratio[((size_t)b * SH + (y >> 3)) * SW + (x >> 3)];
  io[i] = io[i] * r - shiftp[0];
}

}  // namespace

extern "C" void kernel_launch(void* const* d_in, const int* in_sizes, int n_in, void* d_out,
                              int out_size, void* d_ws, size_t ws_size, hipStream_t stream) {
  (void)in_sizes; (void)n_in; (void)out_size; (void)ws_size;
  const float* guide = (const float*)d_in[0];
  const float* source = (const float*)d_in[1];
  const float* mask = (const float*)d_in[2];
  const float* ybic = (const float*)d_in[3];
  float* out = (float*)d_out;

  // Workspace (tail layout identical to the R1/R4 passing runs: proven ws >= 64MB+4KB+512KB):
  //   A   [0,32MB)   full complex spectrum
  //   Bc  [32,48MB)  processed columns (512 x 1024 complex per batch)
  //   er  [32,48MB)  overlays Bc (Bc dead after transpose_bwd; er written after)
  //   cvh [48,64MB)  packed half2 {cv,ch}
  //   itmp[0,16MB)   diffuse ping buffer (A dead after rowfft_inv)
  //   shiftp @64MB, partial @+256B, ratioA @64MB+4KB, ratioB @+256KB
  char* ws = (char*)d_ws;
  float2* A = (float2*)ws;
  float2* Bc = (float2*)(ws + (size_t)32 * 1024 * 1024);
  float* er = (float*)(ws + (size_t)32 * 1024 * 1024);
  __half2* cvh = (__half2*)(ws + (size_t)48 * 1024 * 1024);
  float* itmp = (float*)ws;
  float* shiftp = (float*)(ws + (size_t)64 * 1024 * 1024);
  float* partial = shiftp + 64;
  float* ratioA = (float*)(ws + (size_t)64 * 1024 * 1024 + 4096);
  float* ratioB = ratioA + (size_t)NB * SH * SW;

  k_shift_part<<<64, 256, 0, stream>>>(source, partial);
  k_shift_fin<<<1, 64, 0, stream>>>(partial, shiftp);

  // er_sum = real(ifft2(fft2(sum_c feats_c) * hf_mask))  (linearity over channels)
  k_rowfft_fwd<<<dim3(H, NB), 256, 0, stream>>>(guide, ybic, shiftp, A);
  dim3 gT(NCOL / 32, H / 32, NB), bT(32, 8);
  k_transpose_fwd<<<gT, bT, 0, stream>>>(A, Bc);
  k_colfft_mask<<<dim3(NCOL, NB), 256, 0, stream>>>(Bc);
  k_transpose_bwd<<<gT, bT, 0, stream>>>(Bc, A);
  k_rowfft_inv<<<dim3(H, NB), 256, 0, stream>>>(A, er);

  k_coeffs<<<dim3(H, NB), 256, 0, stream>>>(guide, ybic, er, cvh);

  // 8 x fused { diffuse (prev ratio on load) ; block-mean ratio } with ratio ping-pong
  const float* cur = ybic;
  float* bufs[2] = {itmp, out};
  float* ratios[2] = {ratioA, ratioB};
  const float* rprev = nullptr;
  float* rlast = nullptr;
  for (int it = 0; it < NPRE_IT; ++it) {
    float* dst = bufs[it & 1];
    float* rout = ratios[it & 1];
    k_diffuse_ratio<<<dim3(W / 32, H / 8, NB), dim3(32, 8), 0, stream>>>(
        cur, rprev, shiftp, it == 0 ? 1 : 0, cvh, source, mask, dst, rout);
    cur = dst;
    rprev = rout;
    rlast = rout;
  }
  // d8 lives in d_out (even number of ping-pongs); apply last ratio and subtract shift.
  k_final<<<dim3(NB * H * W / 256), 256, 0, stream>>>(out, rlast, shiftp);
}

// Round 6
// 297.031 us; speedup vs baseline: 1.8965x; 1.5591x over previous
//
#include <hip/hip_runtime.h>
#include <hip/hip_fp16.h>

namespace {

constexpr int H = 1024, W = 1024, NB = 4;
constexpr int SH = 128, SW = 128;
constexpr float LAM = 0.24f;
constexpr float KK = 0.03f * 0.03f;
constexpr float DEPS_V = 0.1f;
constexpr float FFT_SCALE = 1.0f / (1024.0f * 1024.0f);  // ortho fwd+inv combined
// Processed (masked) columns: |x(k2)| <= 0.5  <=>  k2 in [256, 768). Margin to the
// 0.25 boundary ~1.5e-3 >> fp error.
constexpr int COL_LO = 256, NCOL = 512;

__device__ __forceinline__ float2 cadd(float2 a, float2 b) { return make_float2(a.x + b.x, a.y + b.y); }
__device__ __forceinline__ float2 csub(float2 a, float2 b) { return make_float2(a.x - b.x, a.y - b.y); }
__device__ __forceinline__ float2 cmul(float2 a, float2 b) {
  return make_float2(a.x * b.x - a.y * b.y, a.x * b.y + a.y * b.x);
}
__device__ __forceinline__ int phys2(int e) { return e + (e >> 4); }

// ---------------- min(source): 2-stage parallel reduction ----------------
__global__ void k_shift_part(const float* __restrict__ src, float* __restrict__ partial) {
  int t = threadIdx.x;
  int b0 = blockIdx.x * 1024;
  float m = fminf(fminf(src[b0 + t], src[b0 + t + 256]),
                  fminf(src[b0 + t + 512], src[b0 + t + 768]));
  for (int o = 32; o > 0; o >>= 1) m = fminf(m, __shfl_xor(m, o));
  __shared__ float sm[4];
  if ((t & 63) == 0) sm[t >> 6] = m;
  __syncthreads();
  if (t == 0) partial[blockIdx.x] = fminf(fminf(sm[0], sm[1]), fminf(sm[2], sm[3]));
}

__global__ void k_shift_fin(const float* __restrict__ partial, float* __restrict__ shiftp) {
  int t = threadIdx.x;  // 64 threads
  float m = partial[t];
  for (int o = 32; o > 0; o >>= 1) m = fminf(m, __shfl_xor(m, o));
  if (t == 0) shiftp[0] = (m <= DEPS_V) ? DEPS_V : 0.0f;
}

// ---------------- Stockham radix-4 1024-pt FFT (natural in -> natural out) ----------------
template <int NS, bool INV>
__device__ __forceinline__ void r4_butterfly(float2 v[4], int j, float2 r[4]) {
  if (NS > 1) {
    int p = j & (NS - 1);
    float sn, cs;
    sincospif((INV ? 1.0f : -1.0f) * (float)p * (1.0f / (float)(2 * NS)), &sn, &cs);
    float2 w1 = make_float2(cs, sn);
    float2 w2 = cmul(w1, w1);
    float2 w3 = cmul(w2, w1);
    v[1] = cmul(v[1], w1);
    v[2] = cmul(v[2], w2);
    v[3] = cmul(v[3], w3);
  }
  float2 a0 = cadd(v[0], v[2]), a2 = csub(v[0], v[2]);
  float2 a1 = cadd(v[1], v[3]), a3 = csub(v[1], v[3]);
  a3 = INV ? make_float2(-a3.y, a3.x) : make_float2(a3.y, -a3.x);
  r[0] = cadd(a0, a1);
  r[2] = csub(a0, a1);
  r[1] = cadd(a2, a3);
  r[3] = csub(a2, a3);
}

template <int NS, bool INV>
__device__ __forceinline__ void r4_stage_lds(float2 v[4], float2* dst, int j) {
  float2 r[4];
  r4_butterfly<NS, INV>(v, j, r);
  int p = j & (NS - 1);
  int base = ((j - p) << 2) + p;
#pragma unroll
  for (int k = 0; k < 4; ++k) dst[phys2(base + k * NS)] = r[k];
}

__device__ __forceinline__ void lds_load4(const float2* src, float2 v[4], int j) {
#pragma unroll
  for (int k = 0; k < 4; ++k) v[k] = src[phys2(j + k * 256)];
}

template <bool INV>
__device__ void fft1024(float2 v[4], float2* b0, float2* b1, int j) {
  r4_stage_lds<1, INV>(v, b0, j);
  __syncthreads();
  lds_load4(b0, v, j);
  r4_stage_lds<4, INV>(v, b1, j);
  __syncthreads();
  lds_load4(b1, v, j);
  r4_stage_lds<16, INV>(v, b0, j);
  __syncthreads();
  lds_load4(b0, v, j);
  r4_stage_lds<64, INV>(v, b1, j);
  __syncthreads();
  lds_load4(b1, v, j);
  float2 r[4];
  r4_butterfly<256, INV>(v, j, r);
#pragma unroll
  for (int k = 0; k < 4; ++k) v[k] = r[k];
}

// ---------------- forward row FFT, 2 real rows packed per complex transform ----------------
// Z = S(2y) + i*S(2y+1); F0[k] = (Z[k]+conj(Z[-k]))/2, F1[k] = -i(Z[k]-conj(Z[-k]))/2.
__global__ void k_rowfft_fwd(const float* __restrict__ guide, const float* __restrict__ ybic,
                             const float* __restrict__ shiftp, float2* __restrict__ A) {
  __shared__ float2 b0[1088], b1[1088];
  int b = blockIdx.y, y0 = blockIdx.x * 2, j = threadIdx.x;
  float sh = shiftp[0];
  const float* g0 = guide + ((size_t)(b * 3 + 0) * H + y0) * W;
  const float* g1 = guide + ((size_t)(b * 3 + 1) * H + y0) * W;
  const float* g2 = guide + ((size_t)(b * 3 + 2) * H + y0) * W;
  const float* yb = ybic + ((size_t)b * H + y0) * W;
  float2 v[4];
#pragma unroll
  for (int k = 0; k < 4; ++k) {
    int x = j + k * 256;
    float s0 = g0[x] + g1[x] + g2[x] + (yb[x] + sh);
    float s1 = g0[x + W] + g1[x + W] + g2[x + W] + (yb[x + W] + sh);
    v[k] = make_float2(s0, s1);
  }
  fft1024<false>(v, b0, b1, j);
#pragma unroll
  for (int k = 0; k < 4; ++k) b0[phys2(j + k * 256)] = v[k];
  __syncthreads();
  float2* o0 = A + ((size_t)b * H + y0) * W;
  float2* o1 = o0 + W;
#pragma unroll
  for (int k = 0; k < 4; ++k) {
    int m = j + k * 256;
    float2 Zm = v[k];
    float2 Zc = b0[phys2((1024 - m) & 1023)];
    o0[m] = make_float2(0.5f * (Zm.x + Zc.x), 0.5f * (Zm.y - Zc.y));
    o1[m] = make_float2(0.5f * (Zm.y + Zc.y), 0.5f * (Zc.x - Zm.x));
  }
}

// ---------------- half-width transposes: only columns [256,768) round-trip ----------------
__global__ void k_transpose_fwd(const float2* __restrict__ A, float2* __restrict__ Bc) {
  __shared__ float2 tile[32][33];
  int b = blockIdx.z;
  int c0 = blockIdx.x * 32, y0 = blockIdx.y * 32;
  const float2* ip = A + (size_t)b * H * W;
  float2* op = Bc + (size_t)b * NCOL * H;
#pragma unroll
  for (int k = 0; k < 4; ++k)
    tile[threadIdx.y + k * 8][threadIdx.x] =
        ip[(size_t)(y0 + threadIdx.y + k * 8) * W + (COL_LO + c0 + threadIdx.x)];
  __syncthreads();
#pragma unroll
  for (int k = 0; k < 4; ++k)
    op[(size_t)(c0 + threadIdx.y + k * 8) * H + (y0 + threadIdx.x)] =
        tile[threadIdx.x][threadIdx.y + k * 8];
}

__global__ void k_transpose_bwd(const float2* __restrict__ Bc, float2* __restrict__ A) {
  __shared__ float2 tile[32][33];
  int b = blockIdx.z;
  int c0 = blockIdx.x * 32, y0 = blockIdx.y * 32;
  const float2* ip = Bc + (size_t)b * NCOL * H;
  float2* op = A + (size_t)b * H * W;
#pragma unroll
  for (int k = 0; k < 4; ++k)
    tile[threadIdx.y + k * 8][threadIdx.x] =
        ip[(size_t)(c0 + threadIdx.y + k * 8) * H + (y0 + threadIdx.x)];
  __syncthreads();
#pragma unroll
  for (int k = 0; k < 4; ++k)
    op[(size_t)(y0 + threadIdx.y + k * 8) * W + (COL_LO + c0 + threadIdx.x)] =
        tile[threadIdx.x][threadIdx.y + k * 8];
}

// ---------------- column FFT + radial mask + inverse column FFT ----------------
__global__ void k_colfft_mask(float2* __restrict__ Bc) {
  __shared__ float2 b0[1088], b1[1088];
  int b = blockIdx.y, r = blockIdx.x, j = threadIdx.x;
  int k2 = COL_LO + r;
  double xj = -1.0 + 2.0 * (double)k2 / 1023.0;
  double xj2 = xj * xj;
  float2* row = Bc + ((size_t)b * NCOL + r) * H;
  float2 v[4];
#pragma unroll
  for (int k = 0; k < 4; ++k) v[k] = row[j + k * 256];
  fft1024<false>(v, b0, b1, j);
#pragma unroll
  for (int k = 0; k < 4; ++k) {
    int i = j + k * 256;
    double yv = -1.0 + 2.0 * (double)i / 1023.0;
    if (xj2 + yv * yv <= 0.25) v[k] = make_float2(0.0f, 0.0f);
  }
  fft1024<true>(v, b0, b1, j);
#pragma unroll
  for (int k = 0; k < 4; ++k) row[j + k * 256] = v[k];
}

// ---------------- inverse row FFT -> er (skipped cols compensated x1024) ----------------
__global__ void k_rowfft_inv(const float2* __restrict__ A, float* __restrict__ er) {
  __shared__ float2 b0[1088], b1[1088];
  int b = blockIdx.y, y = blockIdx.x, j = threadIdx.x;
  const float2* in = A + ((size_t)b * H + y) * W;
  float2 v[4];
#pragma unroll
  for (int k = 0; k < 4; ++k) v[k] = in[j + k * 256];
  v[0].x *= 1024.0f; v[0].y *= 1024.0f;
  v[3].x *= 1024.0f; v[3].y *= 1024.0f;
  fft1024<true>(v, b0, b1, j);
  float* out = er + ((size_t)b * H + y) * W;
#pragma unroll
  for (int k = 0; k < 4; ++k) out[j + k * 256] = v[k].x * FFT_SCALE;
}

// ---------------- Perona-Malik coefficients, packed half2 {cv, ch}, 4 px/thread ----------
__global__ void k_coeffs(const float* __restrict__ guide, const float* __restrict__ ybic,
                         const float* __restrict__ er, __half2* __restrict__ cvh) {
  int b = blockIdx.y, y = blockIdx.x, t = threadIdx.x;
  int x0 = t * 4;
  const float* g = guide + (size_t)b * 3 * H * W;
  const float* yb = ybic + (size_t)b * H * W;
  const float* e = er + (size_t)b * H * W;
  __half2* cp = cvh + (size_t)b * H * W;
  const size_t CH = (size_t)H * W;
  size_t row = (size_t)y * W + x0;
  float4 a0 = *(const float4*)(g + row);
  float4 a1 = *(const float4*)(g + CH + row);
  float4 a2 = *(const float4*)(g + 2 * CH + row);
  float4 a3 = *(const float4*)(yb + row);
  float4 e0 = *(const float4*)(e + row);
  float A0[5] = {a0.x, a0.y, a0.z, a0.w, 0.f};
  float A1[5] = {a1.x, a1.y, a1.z, a1.w, 0.f};
  float A2[5] = {a2.x, a2.y, a2.z, a2.w, 0.f};
  float A3[5] = {a3.x, a3.y, a3.z, a3.w, 0.f};
  float E0[5] = {e0.x, e0.y, e0.z, e0.w, 0.f};
  bool hasR = (x0 + 4 < W);
  if (hasR) {
    A0[4] = g[row + 4]; A1[4] = g[CH + row + 4]; A2[4] = g[2 * CH + row + 4];
    A3[4] = yb[row + 4]; E0[4] = e[row + 4];
  }
  float B0[4], B1[4], B2[4], B3[4], E1[4];
  bool hasD = (y < H - 1);
  if (hasD) {
    float4 q0 = *(const float4*)(g + row + W);
    float4 q1 = *(const float4*)(g + CH + row + W);
    float4 q2 = *(const float4*)(g + 2 * CH + row + W);
    float4 q3 = *(const float4*)(yb + row + W);
    float4 q4 = *(const float4*)(e + row + W);
    B0[0]=q0.x; B0[1]=q0.y; B0[2]=q0.z; B0[3]=q0.w;
    B1[0]=q1.x; B1[1]=q1.y; B1[2]=q1.z; B1[3]=q1.w;
    B2[0]=q2.x; B2[1]=q2.y; B2[2]=q2.z; B2[3]=q2.w;
    B3[0]=q3.x; B3[1]=q3.y; B3[2]=q3.z; B3[3]=q3.w;
    E1[0]=q4.x; E1[1]=q4.y; E1[2]=q4.z; E1[3]=q4.w;
  }
  __half2 outq[4];
#pragma unroll
  for (int i = 0; i < 4; ++i) {
    float cvv = 0.0f;
    if (hasD) {
      float s = fabsf(B0[i] - A0[i]) + fabsf(B1[i] - A1[i]) +
                fabsf(B2[i] - A2[i]) + fabsf(B3[i] - A3[i]);
      s = (s + E1[i]) * 0.25f;
      cvv = 1.0f / (1.0f + (s * s) / KK);
    }
    float chv = 0.0f;
    if (i < 3 || hasR) {
      float s = fabsf(A0[i + 1] - A0[i]) + fabsf(A1[i + 1] - A1[i]) +
                fabsf(A2[i + 1] - A2[i]) + fabsf(A3[i + 1] - A3[i]);
      s = (s + E0[i + 1]) * 0.25f;
      chv = 1.0f / (1.0f + (s * s) / KK);
    }
    outq[i] = __floats2half2_rn(cvv, chv);
  }
  *(float4*)(cp + row) = *(const float4*)outq;
}

// ---------------- fused diffuse + 8x8 block-mean ratio, 4 px/thread ----------------
// Block (32,8) covers a 128x8 tile = 16 pool blocks. FINAL: apply own ratio + subtract shift.
template <bool FIRST, bool FINAL>
__global__ void k_diffuse_ratio(const float* __restrict__ in, const float* __restrict__ ratio_in,
                                const float* __restrict__ shiftp,
                                const __half2* __restrict__ cvh, const float* __restrict__ src,
                                const float* __restrict__ mask, float* __restrict__ out,
                                float* __restrict__ ratio_out) {
  int b = blockIdx.z, tx = threadIdx.x, ty = threadIdx.y;
  int x0 = blockIdx.x * 128 + tx * 4;
  int y = blockIdx.y * 8 + ty;
  float sh = shiftp[0];
  float addv = FIRST ? sh : 0.0f;
  size_t base = (size_t)b * H * W;
  const float* I = in + base;
  const __half2* cp = cvh + base;
  float rq = 1.f, rup = 1.f, rdn = 1.f, rlf = 1.f, rrt = 1.f;
  if (!FIRST) {
    const float* rb = ratio_in + (size_t)b * SH * SW;
    int bx3 = x0 >> 3, byq = y >> 3;
    rq = rb[byq * SW + bx3];
    rup = (y > 0) ? rb[((y - 1) >> 3) * SW + bx3] : 1.f;
    rdn = (y < H - 1) ? rb[((y + 1) >> 3) * SW + bx3] : 1.f;
    rlf = (x0 > 0) ? rb[byq * SW + ((x0 - 1) >> 3)] : 1.f;
    rrt = (x0 + 4 < W) ? rb[byq * SW + ((x0 + 4) >> 3)] : 1.f;
  }
  size_t row = (size_t)y * W + x0;
  bool hasU = (y > 0), hasD = (y < H - 1);
  float4 c4 = *(const float4*)(I + row);
  float C[4] = {(c4.x + addv) * rq, (c4.y + addv) * rq, (c4.z + addv) * rq, (c4.w + addv) * rq};
  float U[4] = {0, 0, 0, 0}, D[4] = {0, 0, 0, 0};
  if (hasU) {
    float4 u4 = *(const float4*)(I + row - W);
    U[0] = (u4.x + addv) * rup; U[1] = (u4.y + addv) * rup;
    U[2] = (u4.z + addv) * rup; U[3] = (u4.w + addv) * rup;
  }
  if (hasD) {
    float4 d4 = *(const float4*)(I + row + W);
    D[0] = (d4.x + addv) * rdn; D[1] = (d4.y + addv) * rdn;
    D[2] = (d4.z + addv) * rdn; D[3] = (d4.w + addv) * rdn;
  }
  float lf = (x0 > 0) ? (I[row - 1] + addv) * rlf : 0.f;
  float rt = (x0 + 4 < W) ? (I[row + 4] + addv) * rrt : 0.f;
  // coefficients (cv own row, cv row above, ch own row + left scalar)
  float4 ccraw = *(const float4*)(cp + row);
  const __half2* hq = (const __half2*)&ccraw;
  float cvq[4], chq[4];
#pragma unroll
  for (int i = 0; i < 4; ++i) {
    float2 tt = __half22float2(hq[i]);
    cvq[i] = tt.x; chq[i] = tt.y;
  }
  float cvu[4] = {0, 0, 0, 0};
  if (hasU) {
    float4 cu = *(const float4*)(cp + row - W);
    const __half2* hu = (const __half2*)&cu;
#pragma unroll
    for (int i = 0; i < 4; ++i) cvu[i] = __half2float(hu[i].x);
  }
  float chl = (x0 > 0) ? __half2float(cp[row - 1].y) : 0.f;
  float acc[4];
#pragma unroll
  for (int i = 0; i < 4; ++i) {
    float L = (i == 0) ? lf : C[i - 1];
    float R = (i == 3) ? rt : C[i + 1];
    float cL = (i == 0) ? chl : chq[i - 1];
    float a = C[i];
    if (hasD) a += LAM * cvq[i] * (D[i] - C[i]);
    if (hasU) a -= LAM * cvu[i] * (C[i] - U[i]);
    if (i < 3 || x0 + 4 < W) a += LAM * chq[i] * (R - C[i]);
    if (i > 0 || x0 > 0) a -= LAM * cL * (C[i] - L);
    acc[i] = a;
  }
  // 8x8 block-mean -> ratio
  __shared__ float sd[8][32];
  __shared__ float rblk[16];
  sd[ty][tx] = acc[0] + acc[1] + acc[2] + acc[3];
  __syncthreads();
  if (ty == 0) {  // lanes 0..31 of wave 0
    float colsum = 0.f;
#pragma unroll
    for (int r = 0; r < 8; ++r) colsum += sd[r][tx];
    float s = colsum + __shfl_down(colsum, 1);
    if ((tx & 1) == 0) {
      int pb = tx >> 1;
      size_t si = ((size_t)b * SH + blockIdx.y) * SW + (blockIdx.x * 16 + pb);
      float mean = s * (1.0f / 64.0f);
      float rv = (mask[si] < 0.5f) ? 1.0f : (src[si] + sh) / (mean + 1e-8f);
      if (FINAL) rblk[pb] = rv;
      else ratio_out[si] = rv;
    }
  }
  if (FINAL) {
    __syncthreads();
    float rv = rblk[tx >> 1];
    float4 o = make_float4(acc[0] * rv - sh, acc[1] * rv - sh, acc[2] * rv - sh, acc[3] * rv - sh);
    *(float4*)(out + base + row) = o;
  } else {
    *(float4*)(out + base + row) = make_float4(acc[0], acc[1], acc[2], acc[3]);
  }
}

}  // namespace

extern "C" void kernel_launch(void* const* d_in, const int* in_sizes, int n_in, void* d_out,
                              int out_size, void* d_ws, size_t ws_size, hipStream_t stream) {
  (void)in_sizes; (void)n_in; (void)out_size; (void)ws_size;
  const float* guide = (const float*)d_in[0];
  const float* source = (const float*)d_in[1];
  const float* mask = (const float*)d_in[2];
  const float* ybic = (const float*)d_in[3];
  float* out = (float*)d_out;

  char* ws = (char*)d_ws;
  float2* A = (float2*)ws;                                  // [0,32MB)
  float2* Bc = (float2*)(ws + (size_t)32 * 1024 * 1024);    // [32,48MB)
  float* er = (float*)(ws + (size_t)32 * 1024 * 1024);      // overlays Bc (Bc dead first)
  __half2* cvh = (__half2*)(ws + (size_t)48 * 1024 * 1024); // [48,64MB)
  float* itmp = (float*)ws;                                 // overlays A (dead after rowfft_inv)
  float* shiftp = (float*)(ws + (size_t)64 * 1024 * 1024);
  float* partial = shiftp + 64;
  float* ratioA = (float*)(ws + (size_t)64 * 1024 * 1024 + 4096);
  float* ratioB = ratioA + (size_t)NB * SH * SW;

  k_shift_part<<<64, 256, 0, stream>>>(source, partial);
  k_shift_fin<<<1, 64, 0, stream>>>(partial, shiftp);

  k_rowfft_fwd<<<dim3(H / 2, NB), 256, 0, stream>>>(guide, ybic, shiftp, A);
  dim3 gT(NCOL / 32, H / 32, NB), bT(32, 8);
  k_transpose_fwd<<<gT, bT, 0, stream>>>(A, Bc);
  k_colfft_mask<<<dim3(NCOL, NB), 256, 0, stream>>>(Bc);
  k_transpose_bwd<<<gT, bT, 0, stream>>>(Bc, A);
  k_rowfft_inv<<<dim3(H, NB), 256, 0, stream>>>(A, er);

  k_coeffs<<<dim3(H, NB), 256, 0, stream>>>(guide, ybic, er, cvh);

  dim3 gD(W / 128, H / 8, NB), bD(32, 8);
  // it 0: ybic -> itmp (adds shift, no ratio)
  k_diffuse_ratio<true, false><<<gD, bD, 0, stream>>>(ybic, nullptr, shiftp, cvh, source, mask,
                                                      itmp, ratioA);
  // its 1..6: ping-pong
  k_diffuse_ratio<false, false><<<gD, bD, 0, stream>>>(itmp, ratioA, shiftp, cvh, source, mask,
                                                       out, ratioB);
  k_diffuse_ratio<false, false><<<gD, bD, 0, stream>>>(out, ratioB, shiftp, cvh, source, mask,
                                                       itmp, ratioA);
  k_diffuse_ratio<false, false><<<gD, bD, 0, stream>>>(itmp, ratioA, shiftp, cvh, source, mask,
                                                       out, ratioB);
  k_diffuse_ratio<false, false><<<gD, bD, 0, stream>>>(out, ratioB, shiftp, cvh, source, mask,
                                                       itmp, ratioA);
  k_diffuse_ratio<false, false><<<gD, bD, 0, stream>>>(itmp, ratioA, shiftp, cvh, source, mask,
                                                       out, ratioB);
  k_diffuse_ratio<false, false><<<gD, bD, 0, stream>>>(out, ratioB, shiftp, cvh, source, mask,
                                                       itmp, ratioA);
  // it 7 (FINAL): itmp -> out, applies own ratio + subtracts shift in-kernel
  k_diffuse_ratio<false, true><<<gD, bD, 0, stream>>>(itmp, ratioA, shiftp, cvh, source, mask,
                                                      out, ratioB);
}